// Round 2
// baseline (1376.713 us; speedup 1.0000x reference)
//
#include <hip/hip_runtime.h>
#include <math.h>

#define DD 100
#define GB1 1024

// DPP butterfly helpers (ctrl must be a literal -> macros, not functions)
#define DPP_ADD(v, ctrl) ((v) + __int_as_float(__builtin_amdgcn_update_dpp( \
    0, __float_as_int(v), (ctrl), 0xf, 0xf, true)))
#define SWZ16(v) __int_as_float(__builtin_amdgcn_ds_swizzle(__float_as_int(v), 0x401F))

__device__ __forceinline__ float blo(unsigned u){
  union { unsigned i; float f; } c; c.i = u << 16; return c.f;
}
__device__ __forceinline__ float bhi(unsigned u){
  union { unsigned i; float f; } c; c.i = u & 0xFFFF0000u; return c.f;
}
__device__ __forceinline__ unsigned short f2bf(float f){
  unsigned u = __float_as_uint(f);
  unsigned r = (u + 0x7FFFu + ((u >> 16) & 1u)) >> 16;
  return (unsigned short)r;
}
__device__ __forceinline__ float pick9(int i, float mm,
    float s0, float s1, float s2, float s3,
    float c0, float c1, float c2, float c3){
  float v = mm;
  v = (i==1) ? s0 : v; v = (i==2) ? s1 : v; v = (i==3) ? s2 : v; v = (i==4) ? s3 : v;
  v = (i==5) ? c0 : v; v = (i==6) ? c1 : v; v = (i==7) ? c2 : v; v = (i==8) ? c3 : v;
  return v;
}
// Phi(z) = 0.5*(1+erf(z/sqrt2)), Abramowitz-Stegun 7.1.26 (|err| ~1e-6)
__device__ __forceinline__ float phi_fast(float z){
  float x  = z * 0.70710678118654752440f;
  float ax = fabsf(x);
  float t  = __builtin_amdgcn_rcpf(1.0f + 0.3275911f*ax);
  float p  = t*(0.254829592f + t*(-0.284496736f + t*(1.421413741f
           + t*(-1.453152027f + t*1.061405429f))));
  float e  = __expf(-ax*ax);
  float erfv = copysignf(1.0f - p*e, x);
  return 0.5f*(1.0f + erfv);
}

// ---------------- Kernel 1: fused gating + expert mix -> out matrix ----------
// 256 thr = 4 waves, one row per wave per iteration.
// Weights in LDS as 5 float4 "planes": plane q, row idx (idx=seg*100+d):
//   q0 = wg[0..3], q1 = wg[4..7], q2 = {wg8, wn0, wn1, wn2},
//   q3 = wn[3..6], q4 = {wn7, wn8, 0, 0}
// Lanes read consecutive 16B blocks -> conflict-free ds_read_b128.
__global__ __launch_bounds__(256, 3) void k_gating(
    const float* __restrict__ memf, const float* __restrict__ recr,
    const float* __restrict__ spar, const float* __restrict__ nsrc,
    const float* __restrict__ noise, const float* __restrict__ degc,
    const float* __restrict__ wg,   const float* __restrict__ wn,
    const int*   __restrict__ degree,
    float* __restrict__ outm, float* __restrict__ partials, int B)
{
  __shared__ __align__(16) float sW[5*600*4];   // 48 KB
  __shared__ float sC0[DD], sC1[DD];
  __shared__ float sPart[4][18];

  for (int idx = threadIdx.x; idx < 600; idx += 256){
    float g0=wg[idx*9+0], g1=wg[idx*9+1], g2=wg[idx*9+2], g3=wg[idx*9+3];
    float g4=wg[idx*9+4], g5=wg[idx*9+5], g6=wg[idx*9+6], g7=wg[idx*9+7];
    float g8=wg[idx*9+8];
    float n0=wn[idx*9+0], n1=wn[idx*9+1], n2=wn[idx*9+2], n3=wn[idx*9+3];
    float n4=wn[idx*9+4], n5=wn[idx*9+5], n6=wn[idx*9+6], n7=wn[idx*9+7];
    float n8=wn[idx*9+8];
    ((float4*)sW)[0*600+idx] = make_float4(g0,g1,g2,g3);
    ((float4*)sW)[1*600+idx] = make_float4(g4,g5,g6,g7);
    ((float4*)sW)[2*600+idx] = make_float4(g8,n0,n1,n2);
    ((float4*)sW)[3*600+idx] = make_float4(n3,n4,n5,n6);
    ((float4*)sW)[4*600+idx] = make_float4(n7,n8,0.f,0.f);
  }
  for (int i = threadIdx.x; i < DD; i += 256){ sC0[i] = degc[2*i]; sC1[i] = degc[2*i+1]; }
  __syncthreads();

  const int wave = threadIdx.x >> 6, lane = threadIdx.x & 63;
  const int gw = blockIdx.x*4 + wave, nw = gridDim.x*4;
  const int d0 = lane, d1 = lane + 64;
  const bool h1 = (d1 < DD);
  const int dc1 = h1 ? d1 : 0;

  float ldA[9], imA[9];
  #pragma unroll
  for (int e = 0; e < 9; e++){ ldA[e] = 0.f; imA[e] = 0.f; }

  for (int r = gw; r < B; r += nw){
    const int ru = __builtin_amdgcn_readfirstlane(r);
    const float* pm = memf + (size_t)ru*DD;
    const float* ps = spar + (size_t)ru*4*DD;
    const float* pr = recr + (size_t)ru*4*DD;
    const float* pn = nsrc + (size_t)ru*DD;
    float ldg = __logf((float)degree[ru] + 1.0f);
    float sca = sC0[d0] + ldg*sC1[d0];
    float scb = sC0[dc1] + ldg*sC1[dc1];

    float m[2], nv[2], spv[4][2], rcv[4][2], ct[2][6];
    m[0] = fmaxf(pm[d0], 0.f);
    m[1] = h1 ? fmaxf(pm[d1], 0.f) : 0.f;
    nv[0] = pn[d0];
    nv[1] = h1 ? pn[d1] : 0.f;
    #pragma unroll
    for (int e = 0; e < 4; e++){
      spv[e][0] = ps[e*DD + d0] * sca;
      spv[e][1] = h1 ? ps[e*DD + d1] * scb : 0.f;
      rcv[e][0] = fmaxf(pr[e*DD + d0], 0.f);
      rcv[e][1] = h1 ? fmaxf(pr[e*DD + d1], 0.f) : 0.f;
    }
    #pragma unroll
    for (int sl = 0; sl < 2; sl++){
      float rs = (spv[0][sl]+spv[1][sl]+spv[2][sl]+spv[3][sl])*0.25f;
      float rr = (rcv[0][sl]+rcv[1][sl]+rcv[2][sl]+rcv[3][sl])*0.25f;
      float mm = m[sl];
      ct[sl][0] = mm; ct[sl][1] = rs; ct[sl][2] = rr;
      ct[sl][3] = mm + rs + rr; ct[sl][4] = mm*rs*rr; ct[sl][5] = nv[sl];
    }

    float cg[9], cn[9];
    #pragma unroll
    for (int e = 0; e < 9; e++){ cg[e]=0.f; cn[e]=0.f; }
    #pragma unroll
    for (int sl = 0; sl < 2; sl++){
      const int db = sl ? dc1 : d0;
      #pragma unroll
      for (int seg = 0; seg < 6; seg++){
        const int idx = seg*DD + db;
        float4 q0 = ((const float4*)sW)[0*600+idx];
        float4 q1 = ((const float4*)sW)[1*600+idx];
        float4 q2 = ((const float4*)sW)[2*600+idx];
        float4 q3 = ((const float4*)sW)[3*600+idx];
        float4 q4 = ((const float4*)sW)[4*600+idx];
        float cv = ct[sl][seg];
        cg[0] += cv*q0.x; cg[1] += cv*q0.y; cg[2] += cv*q0.z; cg[3] += cv*q0.w;
        cg[4] += cv*q1.x; cg[5] += cv*q1.y; cg[6] += cv*q1.z; cg[7] += cv*q1.w;
        cg[8] += cv*q2.x;
        cn[0] += cv*q2.y; cn[1] += cv*q2.z; cn[2] += cv*q2.w;
        cn[3] += cv*q3.x; cn[4] += cv*q3.y; cn[5] += cv*q3.z; cn[6] += cv*q3.w;
        cn[7] += cv*q4.x; cn[8] += cv*q4.y;
      }
    }

    // butterfly reduce: 4 DPP stages (xor1, xor2, mirror8, mirror16) + xor16 + xor32
    #pragma unroll
    for (int e = 0; e < 9; e++){
      float a = cg[e], b = cn[e];
      a = DPP_ADD(a, 0xB1);  b = DPP_ADD(b, 0xB1);   // quad_perm(1,0,3,2)
      a = DPP_ADD(a, 0x4E);  b = DPP_ADD(b, 0x4E);   // quad_perm(2,3,0,1)
      a = DPP_ADD(a, 0x141); b = DPP_ADD(b, 0x141);  // row_half_mirror
      a = DPP_ADD(a, 0x140); b = DPP_ADD(b, 0x140);  // row_mirror
      a += SWZ16(a);         b += SWZ16(b);          // xor 16 (within 32)
      a += __shfl_xor(a, 32, 64);
      b += __shfl_xor(b, 32, 64);
      cg[e] = a; cn[e] = b;
    }

    float sd[9], nz[9];
    #pragma unroll
    for (int e = 0; e < 9; e++){
      float x = cn[e];
      float spl = fmaxf(x, 0.f) + __logf(1.0f + __expf(-fabsf(x)));
      sd[e] = spl + 0.01f;
      nz[e] = cg[e] + noise[(size_t)ru*9 + e] * sd[e];
    }
    // top-3 (lower index wins ties)
    float v1 = -3.402823e38f, v2 = v1, v3 = v1; int i1 = -1, i2 = -1;
    #pragma unroll
    for (int e = 0; e < 9; e++){
      float v = nz[e];
      if (v > v1){ v3=v2; v2=v1; i2=i1; v1=v; i1=e; }
      else if (v > v2){ v3=v2; v2=v; i2=e; }
      else if (v > v3){ v3=v; }
    }
    float t  = __expf(v2 - v1);
    float g1 = __builtin_amdgcn_rcpf(1.0f + t);
    float g2 = t*g1;
    #pragma unroll
    for (int e = 0; e < 9; e++){
      float thr = (nz[e] > v3) ? v3 : v2;
      float z = (cg[e] - thr)/sd[e] - 0.1f;            // GATE_MEAN = 0.1
      ldA[e] += phi_fast(z);
      imA[e] += (e==i1) ? g1 : ((e==i2) ? g2 : 0.f);
    }
    // expert mix
    float va0 = pick9(i1, m[0], spv[0][0],spv[1][0],spv[2][0],spv[3][0],
                                rcv[0][0],rcv[1][0],rcv[2][0],rcv[3][0]);
    float vb0 = pick9(i2, m[0], spv[0][0],spv[1][0],spv[2][0],spv[3][0],
                                rcv[0][0],rcv[1][0],rcv[2][0],rcv[3][0]);
    outm[(size_t)r*DD + d0] = g1*va0 + g2*vb0;
    if (h1){
      float va1 = pick9(i1, m[1], spv[0][1],spv[1][1],spv[2][1],spv[3][1],
                                  rcv[0][1],rcv[1][1],rcv[2][1],rcv[3][1]);
      float vb1 = pick9(i2, m[1], spv[0][1],spv[1][1],spv[2][1],spv[3][1],
                                  rcv[0][1],rcv[1][1],rcv[2][1],rcv[3][1]);
      outm[(size_t)r*DD + d1] = g1*va1 + g2*vb1;
    }
  }

  if (lane == 0){
    #pragma unroll
    for (int e = 0; e < 9; e++){ sPart[wave][e] = imA[e]; sPart[wave][9+e] = ldA[e]; }
  }
  __syncthreads();
  if (threadIdx.x < 18){
    float s = sPart[0][threadIdx.x] + sPart[1][threadIdx.x]
            + sPart[2][threadIdx.x] + sPart[3][threadIdx.x];
    partials[blockIdx.x*18 + threadIdx.x] = s;
  }
}

// ---------------- Kernel 2: deterministic loss reduction ---------------------
__global__ void k_loss(const float* __restrict__ partials, int nblk,
                       float* __restrict__ dloss)
{
  __shared__ float sS[18][15];
  int t = threadIdx.x;
  if (t < 252){
    int k = t % 18, c = t / 18;   // 14 chunks
    float s = 0.f;
    for (int b = c; b < nblk; b += 14) s += partials[b*18 + k];
    sS[k][c] = s;
  }
  __syncthreads();
  if (t < 18){
    float tot = 0.f;
    #pragma unroll
    for (int c = 0; c < 14; c++) tot += sS[t][c];
    sS[t][14] = tot;
  }
  __syncthreads();
  if (t == 0){
    float mi = 0.f, ml = 0.f;
    #pragma unroll
    for (int e = 0; e < 9; e++){ mi += sS[e][14]; ml += sS[9+e][14]; }
    mi *= (1.f/9.f); ml *= (1.f/9.f);
    float vi = 0.f, vl = 0.f;
    #pragma unroll
    for (int e = 0; e < 9; e++){
      float a = sS[e][14]   - mi; vi += a*a;
      float b = sS[9+e][14] - ml; vl += b*b;
    }
    vi *= (1.f/8.f); vl *= (1.f/8.f);   // ddof=1, n=9
    *dloss = 0.4f * (vi/(mi*mi + 1e-10f) + vl/(ml*ml + 1e-10f));
  }
}

// ---------------- Kernel 3: link-prediction head -----------------------------
__global__ __launch_bounds__(512) void k_edge(
    const float* __restrict__ om,
    const float* __restrict__ sw, const float* __restrict__ sb,
    const float* __restrict__ dw, const float* __restrict__ db,
    const float* __restrict__ ow, const float* __restrict__ ob,
    float* __restrict__ dout, int NE)
{
  __shared__ __align__(4) unsigned short sSW[DD*102];
  __shared__ __align__(4) unsigned short sDW[DD*102];
  __shared__ float sSB[DD], sDB[DD], sOW[DD];

  for (int i = threadIdx.x; i < DD*DD; i += 512){
    int k = i / DD, d = i % DD;
    sSW[d*102 + k] = f2bf(sw[i]);
    sDW[d*102 + k] = f2bf(dw[i]);
  }
  for (int i = threadIdx.x; i < DD; i += 512){ sSB[i]=sb[i]; sDB[i]=db[i]; sOW[i]=ow[i]; }
  __syncthreads();

  const int wave = threadIdx.x >> 6, lane = threadIdx.x & 63;
  const int grp = blockIdx.x*8 + wave;
  const int e0 = grp*4;
  if (e0 >= NE) return;
  const int e0u = __builtin_amdgcn_readfirstlane(e0);
  const float* oS = om + (size_t)e0u*DD;
  const float* oP = om + ((size_t)(NE  + e0u))*DD;
  const float* oN = om + ((size_t)(2*NE + e0u))*DD;
  const int d0 = lane, d1 = lane + 64;
  const bool h1 = (d1 < DD);
  const int dc1 = h1 ? d1 : 0;

  float aS[4][2], aP[4][2], aN[4][2];
  #pragma unroll
  for (int r = 0; r < 4; r++){
    aS[r][0]=0.f; aS[r][1]=0.f; aP[r][0]=0.f; aP[r][1]=0.f; aN[r][0]=0.f; aN[r][1]=0.f;
  }

  for (int k = 0; k < DD; k += 4){
    unsigned uA = *(const unsigned*)&sSW[d0 *102 + k];
    unsigned uB = *(const unsigned*)&sSW[d0 *102 + k + 2];
    unsigned uC = *(const unsigned*)&sSW[dc1*102 + k];
    unsigned uD = *(const unsigned*)&sSW[dc1*102 + k + 2];
    unsigned uE = *(const unsigned*)&sDW[d0 *102 + k];
    unsigned uF = *(const unsigned*)&sDW[d0 *102 + k + 2];
    unsigned uG = *(const unsigned*)&sDW[dc1*102 + k];
    unsigned uH = *(const unsigned*)&sDW[dc1*102 + k + 2];
    float wS00=blo(uA), wS01=bhi(uA), wS02=blo(uB), wS03=bhi(uB);
    float wS10=blo(uC), wS11=bhi(uC), wS12=blo(uD), wS13=bhi(uD);
    float wD00=blo(uE), wD01=bhi(uE), wD02=blo(uF), wD03=bhi(uF);
    float wD10=blo(uG), wD11=bhi(uG), wD12=blo(uH), wD13=bhi(uH);
    #pragma unroll
    for (int r = 0; r < 4; r++){
      float4 ov = *(const float4*)(oS + r*DD + k);
      float4 pv = *(const float4*)(oP + r*DD + k);
      float4 nv = *(const float4*)(oN + r*DD + k);
      aS[r][0] += ov.x*wS00 + ov.y*wS01 + ov.z*wS02 + ov.w*wS03;
      aS[r][1] += ov.x*wS10 + ov.y*wS11 + ov.z*wS12 + ov.w*wS13;
      aP[r][0] += pv.x*wD00 + pv.y*wD01 + pv.z*wD02 + pv.w*wD03;
      aP[r][1] += pv.x*wD10 + pv.y*wD11 + pv.z*wD12 + pv.w*wD13;
      aN[r][0] += nv.x*wD00 + nv.y*wD01 + nv.z*wD02 + nv.w*wD03;
      aN[r][1] += nv.x*wD10 + nv.y*wD11 + nv.z*wD12 + nv.w*wD13;
    }
  }

  float owa = sOW[d0], owb = sOW[dc1];
  float sba = sSB[d0], sbb = sSB[dc1];
  float dba = sDB[d0], dbb = sDB[dc1];
  float ob0 = ob[0];
  #pragma unroll
  for (int r = 0; r < 4; r++){
    float hs0 = aS[r][0] + sba, hp0 = aP[r][0] + dba, hn0 = aN[r][0] + dba;
    float tp = fmaxf(hs0 + hp0, 0.f)*owa;
    float tn = fmaxf(hs0 + hn0, 0.f)*owa;
    if (h1){
      float hs1 = aS[r][1] + sbb, hp1 = aP[r][1] + dbb, hn1 = aN[r][1] + dbb;
      tp += fmaxf(hs1 + hp1, 0.f)*owb;
      tn += fmaxf(hs1 + hn1, 0.f)*owb;
    }
    #pragma unroll
    for (int off = 32; off > 0; off >>= 1){
      tp += __shfl_xor(tp, off, 64);
      tn += __shfl_xor(tn, off, 64);
    }
    if (lane == 0){
      dout[e0 + r]      = tp + ob0;
      dout[NE + e0 + r] = tn + ob0;
    }
  }
}

extern "C" void kernel_launch(void* const* d_in, const int* in_sizes, int n_in,
                              void* d_out, int out_size, void* d_ws, size_t ws_size,
                              hipStream_t stream)
{
  (void)n_in; (void)out_size; (void)ws_size;
  const float* memf  = (const float*)d_in[0];
  const float* recr  = (const float*)d_in[1];
  const float* spar  = (const float*)d_in[2];
  const float* nsrc  = (const float*)d_in[3];
  const float* noise = (const float*)d_in[4];
  const float* degc  = (const float*)d_in[5];
  const float* wg    = (const float*)d_in[6];
  const float* wn    = (const float*)d_in[7];
  const float* sw    = (const float*)d_in[8];
  const float* sb    = (const float*)d_in[9];
  const float* dw    = (const float*)d_in[10];
  const float* db    = (const float*)d_in[11];
  const float* ow    = (const float*)d_in[12];
  const float* ob    = (const float*)d_in[13];
  const int*   deg   = (const int*)d_in[14];

  const int B  = in_sizes[0] / DD;     // 90000
  const int NE = B / 3;                // 30000
  float* outm     = (float*)d_ws;
  float* partials = outm + (size_t)B*DD;
  float* dout     = (float*)d_out;

  k_gating<<<dim3(GB1), dim3(256), 0, stream>>>(memf, recr, spar, nsrc, noise,
                                                degc, wg, wn, deg, outm, partials, B);
  k_loss<<<dim3(1), dim3(256), 0, stream>>>(partials, GB1, dout + 2*NE);
  const int blocks2 = (NE/4 + 7) / 8;  // 938
  k_edge<<<dim3(blocks2), dim3(512), 0, stream>>>(outm, sw, sb, dw, db, ow, ob, dout, NE);
}

// Round 3
// 716.869 us; speedup vs baseline: 1.9205x; 1.9205x over previous
//
#include <hip/hip_runtime.h>
#include <math.h>

#define DD 100
#define GB1 1536

// DPP butterfly helpers (ctrl must be a literal -> macros, not functions)
#define DPP_ADD(v, ctrl) ((v) + __int_as_float(__builtin_amdgcn_update_dpp( \
    0, __float_as_int(v), (ctrl), 0xf, 0xf, true)))
#define SWZ16(v) __int_as_float(__builtin_amdgcn_ds_swizzle(__float_as_int(v), 0x401F))

__device__ __forceinline__ float blo(unsigned u){
  union { unsigned i; float f; } c; c.i = u << 16; return c.f;
}
__device__ __forceinline__ float bhi(unsigned u){
  union { unsigned i; float f; } c; c.i = u & 0xFFFF0000u; return c.f;
}
__device__ __forceinline__ unsigned short f2bf(float f){
  unsigned u = __float_as_uint(f);
  unsigned r = (u + 0x7FFFu + ((u >> 16) & 1u)) >> 16;
  return (unsigned short)r;
}
__device__ __forceinline__ float pick9(int i, float mm,
    float s0, float s1, float s2, float s3,
    float c0, float c1, float c2, float c3){
  float v = mm;
  v = (i==1) ? s0 : v; v = (i==2) ? s1 : v; v = (i==3) ? s2 : v; v = (i==4) ? s3 : v;
  v = (i==5) ? c0 : v; v = (i==6) ? c1 : v; v = (i==7) ? c2 : v; v = (i==8) ? c3 : v;
  return v;
}
// Phi(z) = 0.5*(1+erf(z/sqrt2)), Abramowitz-Stegun 7.1.26 (|err| ~1e-6)
__device__ __forceinline__ float phi_fast(float z){
  float x  = z * 0.70710678118654752440f;
  float ax = fabsf(x);
  float t  = __builtin_amdgcn_rcpf(1.0f + 0.3275911f*ax);
  float p  = t*(0.254829592f + t*(-0.284496736f + t*(1.421413741f
           + t*(-1.453152027f + t*1.061405429f))));
  float e  = __expf(-ax*ax);
  float erfv = copysignf(1.0f - p*e, x);
  return 0.5f*(1.0f + erfv);
}

// ---------------- Kernel 1: fused gating + expert mix -> out matrix ----------
// 256 thr = 4 waves, one row per wave per iteration.
// Weights in LDS as 5 float4 "planes" (48 KB), conflict-free ds_read_b128.
// NOTE: no min-waves launch-bounds hint — R2 showed it forces VGPR=84 + spill
// (FETCH 6x, WRITE 6x). Let the allocator pick (~R1: 224 VGPR, no spill).
__global__ __launch_bounds__(256) void k_gating(
    const float* __restrict__ memf, const float* __restrict__ recr,
    const float* __restrict__ spar, const float* __restrict__ nsrc,
    const float* __restrict__ noise, const float* __restrict__ degc,
    const float* __restrict__ wg,   const float* __restrict__ wn,
    const int*   __restrict__ degree,
    float* __restrict__ outm, float* __restrict__ partials, int B)
{
  __shared__ __align__(16) float sW[5*600*4];   // 48 KB
  __shared__ float sC0[DD], sC1[DD];
  __shared__ float sPart[4][18];

  for (int idx = threadIdx.x; idx < 600; idx += 256){
    float g0=wg[idx*9+0], g1=wg[idx*9+1], g2=wg[idx*9+2], g3=wg[idx*9+3];
    float g4=wg[idx*9+4], g5=wg[idx*9+5], g6=wg[idx*9+6], g7=wg[idx*9+7];
    float g8=wg[idx*9+8];
    float n0=wn[idx*9+0], n1=wn[idx*9+1], n2=wn[idx*9+2], n3=wn[idx*9+3];
    float n4=wn[idx*9+4], n5=wn[idx*9+5], n6=wn[idx*9+6], n7=wn[idx*9+7];
    float n8=wn[idx*9+8];
    ((float4*)sW)[0*600+idx] = make_float4(g0,g1,g2,g3);
    ((float4*)sW)[1*600+idx] = make_float4(g4,g5,g6,g7);
    ((float4*)sW)[2*600+idx] = make_float4(g8,n0,n1,n2);
    ((float4*)sW)[3*600+idx] = make_float4(n3,n4,n5,n6);
    ((float4*)sW)[4*600+idx] = make_float4(n7,n8,0.f,0.f);
  }
  for (int i = threadIdx.x; i < DD; i += 256){ sC0[i] = degc[2*i]; sC1[i] = degc[2*i+1]; }
  __syncthreads();

  const int wave = threadIdx.x >> 6, lane = threadIdx.x & 63;
  const int gw = blockIdx.x*4 + wave, nw = gridDim.x*4;
  const int d0 = lane, d1 = lane + 64;
  const bool h1 = (d1 < DD);
  const int dc1 = h1 ? d1 : 0;

  float ldA[9], imA[9];
  #pragma unroll
  for (int e = 0; e < 9; e++){ ldA[e] = 0.f; imA[e] = 0.f; }

  for (int r = gw; r < B; r += nw){
    const int ru = __builtin_amdgcn_readfirstlane(r);
    const float* pm = memf + (size_t)ru*DD;
    const float* ps = spar + (size_t)ru*4*DD;
    const float* pr = recr + (size_t)ru*4*DD;
    const float* pn = nsrc + (size_t)ru*DD;
    float nzl[9];
    #pragma unroll
    for (int e = 0; e < 9; e++) nzl[e] = noise[(size_t)ru*9 + e];
    float ldg = __logf((float)degree[ru] + 1.0f);
    float sca = sC0[d0] + ldg*sC1[d0];
    float scb = sC0[dc1] + ldg*sC1[dc1];

    float m[2], nv[2], spv[4][2], rcv[4][2], ct[2][6];
    m[0] = fmaxf(pm[d0], 0.f);
    m[1] = h1 ? fmaxf(pm[d1], 0.f) : 0.f;
    nv[0] = pn[d0];
    nv[1] = h1 ? pn[d1] : 0.f;
    #pragma unroll
    for (int e = 0; e < 4; e++){
      spv[e][0] = ps[e*DD + d0] * sca;
      spv[e][1] = h1 ? ps[e*DD + d1] * scb : 0.f;
      rcv[e][0] = fmaxf(pr[e*DD + d0], 0.f);
      rcv[e][1] = h1 ? fmaxf(pr[e*DD + d1], 0.f) : 0.f;
    }
    #pragma unroll
    for (int sl = 0; sl < 2; sl++){
      float rs = (spv[0][sl]+spv[1][sl]+spv[2][sl]+spv[3][sl])*0.25f;
      float rr = (rcv[0][sl]+rcv[1][sl]+rcv[2][sl]+rcv[3][sl])*0.25f;
      float mm = m[sl];
      ct[sl][0] = mm; ct[sl][1] = rs; ct[sl][2] = rr;
      ct[sl][3] = mm + rs + rr; ct[sl][4] = mm*rs*rr; ct[sl][5] = nv[sl];
    }

    float cg[9], cn[9];
    #pragma unroll
    for (int e = 0; e < 9; e++){ cg[e]=0.f; cn[e]=0.f; }
    #pragma unroll
    for (int sl = 0; sl < 2; sl++){
      const int db = sl ? dc1 : d0;
      #pragma unroll
      for (int seg = 0; seg < 6; seg++){
        const int idx = seg*DD + db;
        float4 q0 = ((const float4*)sW)[0*600+idx];
        float4 q1 = ((const float4*)sW)[1*600+idx];
        float4 q2 = ((const float4*)sW)[2*600+idx];
        float4 q3 = ((const float4*)sW)[3*600+idx];
        float4 q4 = ((const float4*)sW)[4*600+idx];
        float cv = ct[sl][seg];
        cg[0] += cv*q0.x; cg[1] += cv*q0.y; cg[2] += cv*q0.z; cg[3] += cv*q0.w;
        cg[4] += cv*q1.x; cg[5] += cv*q1.y; cg[6] += cv*q1.z; cg[7] += cv*q1.w;
        cg[8] += cv*q2.x;
        cn[0] += cv*q2.y; cn[1] += cv*q2.z; cn[2] += cv*q2.w;
        cn[3] += cv*q3.x; cn[4] += cv*q3.y; cn[5] += cv*q3.z; cn[6] += cv*q3.w;
        cn[7] += cv*q4.x; cn[8] += cv*q4.y;
      }
    }

    // butterfly reduce: 4 DPP stages + ds_swizzle xor16 + shfl xor32
    #pragma unroll
    for (int e = 0; e < 9; e++){
      float a = cg[e], b = cn[e];
      a = DPP_ADD(a, 0xB1);  b = DPP_ADD(b, 0xB1);   // quad_perm(1,0,3,2)
      a = DPP_ADD(a, 0x4E);  b = DPP_ADD(b, 0x4E);   // quad_perm(2,3,0,1)
      a = DPP_ADD(a, 0x141); b = DPP_ADD(b, 0x141);  // row_half_mirror
      a = DPP_ADD(a, 0x140); b = DPP_ADD(b, 0x140);  // row_mirror
      a += SWZ16(a);         b += SWZ16(b);          // xor 16 (within 32)
      a += __shfl_xor(a, 32, 64);
      b += __shfl_xor(b, 32, 64);
      cg[e] = a; cn[e] = b;
    }

    float sd[9], nz[9];
    #pragma unroll
    for (int e = 0; e < 9; e++){
      float x = cn[e];
      float spl = fmaxf(x, 0.f) + __logf(1.0f + __expf(-fabsf(x)));
      sd[e] = spl + 0.01f;
      nz[e] = cg[e] + nzl[e] * sd[e];
    }
    // top-3 (lower index wins ties)
    float v1 = -3.402823e38f, v2 = v1, v3 = v1; int i1 = -1, i2 = -1;
    #pragma unroll
    for (int e = 0; e < 9; e++){
      float v = nz[e];
      if (v > v1){ v3=v2; v2=v1; i2=i1; v1=v; i1=e; }
      else if (v > v2){ v3=v2; v2=v; i2=e; }
      else if (v > v3){ v3=v; }
    }
    float t  = __expf(v2 - v1);
    float g1 = __builtin_amdgcn_rcpf(1.0f + t);
    float g2 = t*g1;
    #pragma unroll
    for (int e = 0; e < 9; e++){
      float thr = (nz[e] > v3) ? v3 : v2;
      float z = (cg[e] - thr)/sd[e] - 0.1f;            // GATE_MEAN = 0.1
      ldA[e] += phi_fast(z);
      imA[e] += (e==i1) ? g1 : ((e==i2) ? g2 : 0.f);
    }
    // expert mix
    float va0 = pick9(i1, m[0], spv[0][0],spv[1][0],spv[2][0],spv[3][0],
                                rcv[0][0],rcv[1][0],rcv[2][0],rcv[3][0]);
    float vb0 = pick9(i2, m[0], spv[0][0],spv[1][0],spv[2][0],spv[3][0],
                                rcv[0][0],rcv[1][0],rcv[2][0],rcv[3][0]);
    outm[(size_t)r*DD + d0] = g1*va0 + g2*vb0;
    if (h1){
      float va1 = pick9(i1, m[1], spv[0][1],spv[1][1],spv[2][1],spv[3][1],
                                  rcv[0][1],rcv[1][1],rcv[2][1],rcv[3][1]);
      float vb1 = pick9(i2, m[1], spv[0][1],spv[1][1],spv[2][1],spv[3][1],
                                  rcv[0][1],rcv[1][1],rcv[2][1],rcv[3][1]);
      outm[(size_t)r*DD + d1] = g1*va1 + g2*vb1;
    }
  }

  if (lane == 0){
    #pragma unroll
    for (int e = 0; e < 9; e++){ sPart[wave][e] = imA[e]; sPart[wave][9+e] = ldA[e]; }
  }
  __syncthreads();
  if (threadIdx.x < 18){
    float s = sPart[0][threadIdx.x] + sPart[1][threadIdx.x]
            + sPart[2][threadIdx.x] + sPart[3][threadIdx.x];
    partials[blockIdx.x*18 + threadIdx.x] = s;
  }
}

// ---------------- Kernel 2: deterministic loss reduction ---------------------
__global__ void k_loss(const float* __restrict__ partials, int nblk,
                       float* __restrict__ dloss)
{
  __shared__ float sS[18][15];
  int t = threadIdx.x;
  if (t < 252){
    int k = t % 18, c = t / 18;   // 14 chunks
    float s = 0.f;
    for (int b = c; b < nblk; b += 14) s += partials[b*18 + k];
    sS[k][c] = s;
  }
  __syncthreads();
  if (t < 18){
    float tot = 0.f;
    #pragma unroll
    for (int c = 0; c < 14; c++) tot += sS[t][c];
    sS[t][14] = tot;
  }
  __syncthreads();
  if (t == 0){
    float mi = 0.f, ml = 0.f;
    #pragma unroll
    for (int e = 0; e < 9; e++){ mi += sS[e][14]; ml += sS[9+e][14]; }
    mi *= (1.f/9.f); ml *= (1.f/9.f);
    float vi = 0.f, vl = 0.f;
    #pragma unroll
    for (int e = 0; e < 9; e++){
      float a = sS[e][14]   - mi; vi += a*a;
      float b = sS[9+e][14] - ml; vl += b*b;
    }
    vi *= (1.f/8.f); vl *= (1.f/8.f);   // ddof=1, n=9
    *dloss = 0.4f * (vi/(mi*mi + 1e-10f) + vl/(ml*ml + 1e-10f));
  }
}

// ---------------- Kernel 3: link-prediction head -----------------------------
__global__ __launch_bounds__(512) void k_edge(
    const float* __restrict__ om,
    const float* __restrict__ sw, const float* __restrict__ sb,
    const float* __restrict__ dw, const float* __restrict__ db,
    const float* __restrict__ ow, const float* __restrict__ ob,
    float* __restrict__ dout, int NE)
{
  __shared__ __align__(4) unsigned short sSW[DD*102];
  __shared__ __align__(4) unsigned short sDW[DD*102];
  __shared__ float sSB[DD], sDB[DD], sOW[DD];

  for (int i = threadIdx.x; i < DD*DD; i += 512){
    int k = i / DD, d = i % DD;
    sSW[d*102 + k] = f2bf(sw[i]);
    sDW[d*102 + k] = f2bf(dw[i]);
  }
  for (int i = threadIdx.x; i < DD; i += 512){ sSB[i]=sb[i]; sDB[i]=db[i]; sOW[i]=ow[i]; }
  __syncthreads();

  const int wave = threadIdx.x >> 6, lane = threadIdx.x & 63;
  const int grp = blockIdx.x*8 + wave;
  const int e0 = grp*4;
  if (e0 >= NE) return;
  const int e0u = __builtin_amdgcn_readfirstlane(e0);
  const float* oS = om + (size_t)e0u*DD;
  const float* oP = om + ((size_t)(NE  + e0u))*DD;
  const float* oN = om + ((size_t)(2*NE + e0u))*DD;
  const int d0 = lane, d1 = lane + 64;
  const bool h1 = (d1 < DD);
  const int dc1 = h1 ? d1 : 0;

  float aS[4][2], aP[4][2], aN[4][2];
  #pragma unroll
  for (int r = 0; r < 4; r++){
    aS[r][0]=0.f; aS[r][1]=0.f; aP[r][0]=0.f; aP[r][1]=0.f; aN[r][0]=0.f; aN[r][1]=0.f;
  }

  for (int k = 0; k < DD; k += 4){
    unsigned uA = *(const unsigned*)&sSW[d0 *102 + k];
    unsigned uB = *(const unsigned*)&sSW[d0 *102 + k + 2];
    unsigned uC = *(const unsigned*)&sSW[dc1*102 + k];
    unsigned uD = *(const unsigned*)&sSW[dc1*102 + k + 2];
    unsigned uE = *(const unsigned*)&sDW[d0 *102 + k];
    unsigned uF = *(const unsigned*)&sDW[d0 *102 + k + 2];
    unsigned uG = *(const unsigned*)&sDW[dc1*102 + k];
    unsigned uH = *(const unsigned*)&sDW[dc1*102 + k + 2];
    float wS00=blo(uA), wS01=bhi(uA), wS02=blo(uB), wS03=bhi(uB);
    float wS10=blo(uC), wS11=bhi(uC), wS12=blo(uD), wS13=bhi(uD);
    float wD00=blo(uE), wD01=bhi(uE), wD02=blo(uF), wD03=bhi(uF);
    float wD10=blo(uG), wD11=bhi(uG), wD12=blo(uH), wD13=bhi(uH);
    #pragma unroll
    for (int r = 0; r < 4; r++){
      float4 ov = *(const float4*)(oS + r*DD + k);
      float4 pv = *(const float4*)(oP + r*DD + k);
      float4 nv = *(const float4*)(oN + r*DD + k);
      aS[r][0] += ov.x*wS00 + ov.y*wS01 + ov.z*wS02 + ov.w*wS03;
      aS[r][1] += ov.x*wS10 + ov.y*wS11 + ov.z*wS12 + ov.w*wS13;
      aP[r][0] += pv.x*wD00 + pv.y*wD01 + pv.z*wD02 + pv.w*wD03;
      aP[r][1] += pv.x*wD10 + pv.y*wD11 + pv.z*wD12 + pv.w*wD13;
      aN[r][0] += nv.x*wD00 + nv.y*wD01 + nv.z*wD02 + nv.w*wD03;
      aN[r][1] += nv.x*wD10 + nv.y*wD11 + nv.z*wD12 + nv.w*wD13;
    }
  }

  float owa = sOW[d0], owb = sOW[dc1];
  float sba = sSB[d0], sbb = sSB[dc1];
  float dba = sDB[d0], dbb = sDB[dc1];
  float ob0 = ob[0];
  #pragma unroll
  for (int r = 0; r < 4; r++){
    float hs0 = aS[r][0] + sba, hp0 = aP[r][0] + dba, hn0 = aN[r][0] + dba;
    float tp = fmaxf(hs0 + hp0, 0.f)*owa;
    float tn = fmaxf(hs0 + hn0, 0.f)*owa;
    if (h1){
      float hs1 = aS[r][1] + sbb, hp1 = aP[r][1] + dbb, hn1 = aN[r][1] + dbb;
      tp += fmaxf(hs1 + hp1, 0.f)*owb;
      tn += fmaxf(hs1 + hn1, 0.f)*owb;
    }
    #pragma unroll
    for (int off = 32; off > 0; off >>= 1){
      tp += __shfl_xor(tp, off, 64);
      tn += __shfl_xor(tn, off, 64);
    }
    if (lane == 0){
      dout[e0 + r]      = tp + ob0;
      dout[NE + e0 + r] = tn + ob0;
    }
  }
}

extern "C" void kernel_launch(void* const* d_in, const int* in_sizes, int n_in,
                              void* d_out, int out_size, void* d_ws, size_t ws_size,
                              hipStream_t stream)
{
  (void)n_in; (void)out_size; (void)ws_size;
  const float* memf  = (const float*)d_in[0];
  const float* recr  = (const float*)d_in[1];
  const float* spar  = (const float*)d_in[2];
  const float* nsrc  = (const float*)d_in[3];
  const float* noise = (const float*)d_in[4];
  const float* degc  = (const float*)d_in[5];
  const float* wg    = (const float*)d_in[6];
  const float* wn    = (const float*)d_in[7];
  const float* sw    = (const float*)d_in[8];
  const float* sb    = (const float*)d_in[9];
  const float* dw    = (const float*)d_in[10];
  const float* db    = (const float*)d_in[11];
  const float* ow    = (const float*)d_in[12];
  const float* ob    = (const float*)d_in[13];
  const int*   deg   = (const int*)d_in[14];

  const int B  = in_sizes[0] / DD;     // 90000
  const int NE = B / 3;                // 30000
  float* outm     = (float*)d_ws;
  float* partials = outm + (size_t)B*DD;
  float* dout     = (float*)d_out;

  k_gating<<<dim3(GB1), dim3(256), 0, stream>>>(memf, recr, spar, nsrc, noise,
                                                degc, wg, wn, deg, outm, partials, B);
  k_loss<<<dim3(1), dim3(256), 0, stream>>>(partials, GB1, dout + 2*NE);
  const int blocks2 = (NE/4 + 7) / 8;  // 938
  k_edge<<<dim3(blocks2), dim3(512), 0, stream>>>(outm, sw, sb, dw, db, ow, ob, dout, NE);
}

// Round 4
// 679.606 us; speedup vs baseline: 2.0257x; 1.0548x over previous
//
#include <hip/hip_runtime.h>
#include <math.h>

#define DD 100
#define GB1 1024

// DPP butterfly helpers (ctrl must be a literal -> macros, not functions)
#define DPP_ADD(v, ctrl) ((v) + __int_as_float(__builtin_amdgcn_update_dpp( \
    0, __float_as_int(v), (ctrl), 0xf, 0xf, true)))
#define SWZ16(v) __int_as_float(__builtin_amdgcn_ds_swizzle(__float_as_int(v), 0x401F))

__device__ __forceinline__ float blo(unsigned u){
  union { unsigned i; float f; } c; c.i = u << 16; return c.f;
}
__device__ __forceinline__ float bhi(unsigned u){
  union { unsigned i; float f; } c; c.i = u & 0xFFFF0000u; return c.f;
}
__device__ __forceinline__ unsigned short f2bf(float f){
  unsigned u = __float_as_uint(f);
  unsigned r = (u + 0x7FFFu + ((u >> 16) & 1u)) >> 16;
  return (unsigned short)r;
}
__device__ __forceinline__ float pick9(int i, float mm,
    float s0, float s1, float s2, float s3,
    float c0, float c1, float c2, float c3){
  float v = mm;
  v = (i==1) ? s0 : v; v = (i==2) ? s1 : v; v = (i==3) ? s2 : v; v = (i==4) ? s3 : v;
  v = (i==5) ? c0 : v; v = (i==6) ? c1 : v; v = (i==7) ? c2 : v; v = (i==8) ? c3 : v;
  return v;
}
// Phi(z) = 0.5*(1+erf(z/sqrt2)), Abramowitz-Stegun 7.1.26 (|err| ~1e-6)
__device__ __forceinline__ float phi_fast(float z){
  float x  = z * 0.70710678118654752440f;
  float ax = fabsf(x);
  float t  = __builtin_amdgcn_rcpf(1.0f + 0.3275911f*ax);
  float p  = t*(0.254829592f + t*(-0.284496736f + t*(1.421413741f
           + t*(-1.453152027f + t*1.061405429f))));
  float e  = __expf(-ax*ax);
  float erfv = copysignf(1.0f - p*e, x);
  return 0.5f*(1.0f + erfv);
}

// ---------------- Kernel 1: fused gating + expert mix -> out matrix ----------
// 256 thr = 4 waves, TWO rows per wave per iteration (independent chains = ILP).
// Segment folding: cat@W = mem@(W0+W3) + rs@(W1+W3) + rr@(W2+W3) + x2@W4 + ns@W5
// -> 5 segments, weights pre-combined at staging. LDS 40 KB, float4 planes.
__global__ __launch_bounds__(256) void k_gating(
    const float* __restrict__ memf, const float* __restrict__ recr,
    const float* __restrict__ spar, const float* __restrict__ nsrc,
    const float* __restrict__ noise, const float* __restrict__ degc,
    const float* __restrict__ wg,   const float* __restrict__ wn,
    const int*   __restrict__ degree,
    float* __restrict__ outm, float* __restrict__ partials, int B)
{
  __shared__ __align__(16) float sW[5*500*4];   // 40 KB
  __shared__ float sC0[DD], sC1[DD];
  __shared__ float sPart[4][18];

  for (int i2 = threadIdx.x; i2 < 500; i2 += 256){
    int s = i2/100, d = i2%100;
    int rA = (s==0) ? d : (s==1) ? 100+d : (s==2) ? 200+d : (s==3) ? 400+d : 500+d;
    int rB = 300+d;
    bool add3 = (s < 3);
    float g[9], n[9];
    #pragma unroll
    for (int e = 0; e < 9; e++){
      g[e] = wg[rA*9+e] + (add3 ? wg[rB*9+e] : 0.f);
      n[e] = wn[rA*9+e] + (add3 ? wn[rB*9+e] : 0.f);
    }
    ((float4*)sW)[0*500+i2] = make_float4(g[0],g[1],g[2],g[3]);
    ((float4*)sW)[1*500+i2] = make_float4(g[4],g[5],g[6],g[7]);
    ((float4*)sW)[2*500+i2] = make_float4(g[8],n[0],n[1],n[2]);
    ((float4*)sW)[3*500+i2] = make_float4(n[3],n[4],n[5],n[6]);
    ((float4*)sW)[4*500+i2] = make_float4(n[7],n[8],0.f,0.f);
  }
  for (int i = threadIdx.x; i < DD; i += 256){ sC0[i] = degc[2*i]; sC1[i] = degc[2*i+1]; }
  __syncthreads();

  const int wave = threadIdx.x >> 6, lane = threadIdx.x & 63;
  const int gw = blockIdx.x*4 + wave, nw = gridDim.x*4;
  const int d0 = lane, d1 = lane + 64;
  const bool h1 = (d1 < DD);
  const int dc1 = h1 ? d1 : 0;

  float ldA[9], imA[9];
  #pragma unroll
  for (int e = 0; e < 9; e++){ ldA[e] = 0.f; imA[e] = 0.f; }

  const int npair = B >> 1;
  for (int p = gw; p < npair; p += nw){
    float m[2][2], spv[2][4][2], rcv[2][4][2], ct[2][2][5];
    float nzl[2][9];
    #pragma unroll
    for (int rw = 0; rw < 2; rw++){
      const int r = 2*p + rw;
      const int ru = __builtin_amdgcn_readfirstlane(r);
      const float* pm = memf + (size_t)ru*DD;
      const float* ps = spar + (size_t)ru*4*DD;
      const float* pr = recr + (size_t)ru*4*DD;
      const float* pn = nsrc + (size_t)ru*DD;
      #pragma unroll
      for (int e = 0; e < 9; e++) nzl[rw][e] = noise[(size_t)ru*9 + e];
      float ldg = __logf((float)degree[ru] + 1.0f);
      float sca = sC0[d0] + ldg*sC1[d0];
      float scb = sC0[dc1] + ldg*sC1[dc1];
      m[rw][0] = fmaxf(pm[d0], 0.f);
      m[rw][1] = h1 ? fmaxf(pm[d1], 0.f) : 0.f;
      float nsa = pn[d0];
      float nsb = h1 ? pn[d1] : 0.f;
      #pragma unroll
      for (int e = 0; e < 4; e++){
        spv[rw][e][0] = ps[e*DD + d0] * sca;
        spv[rw][e][1] = h1 ? ps[e*DD + d1] * scb : 0.f;
        rcv[rw][e][0] = fmaxf(pr[e*DD + d0], 0.f);
        rcv[rw][e][1] = h1 ? fmaxf(pr[e*DD + d1], 0.f) : 0.f;
      }
      #pragma unroll
      for (int sl = 0; sl < 2; sl++){
        float rs = (spv[rw][0][sl]+spv[rw][1][sl]+spv[rw][2][sl]+spv[rw][3][sl])*0.25f;
        float rr = (rcv[rw][0][sl]+rcv[rw][1][sl]+rcv[rw][2][sl]+rcv[rw][3][sl])*0.25f;
        float mm = m[rw][sl];
        ct[rw][sl][0] = mm; ct[rw][sl][1] = rs; ct[rw][sl][2] = rr;
        ct[rw][sl][3] = mm*rs*rr; ct[rw][sl][4] = (sl==0) ? nsa : nsb;
      }
    }

    // GEMV partials over 5 folded segments; LDS reads shared across the 2 rows
    float cg[2][9], cn[2][9];
    #pragma unroll
    for (int e = 0; e < 9; e++){ cg[0][e]=0.f; cg[1][e]=0.f; cn[0][e]=0.f; cn[1][e]=0.f; }
    #pragma unroll
    for (int sl = 0; sl < 2; sl++){
      const int db = sl ? dc1 : d0;
      #pragma unroll
      for (int seg = 0; seg < 5; seg++){
        const int idx = seg*DD + db;
        float4 q0 = ((const float4*)sW)[0*500+idx];
        float4 q1 = ((const float4*)sW)[1*500+idx];
        float4 q2 = ((const float4*)sW)[2*500+idx];
        float4 q3 = ((const float4*)sW)[3*500+idx];
        float4 q4 = ((const float4*)sW)[4*500+idx];
        #pragma unroll
        for (int rw = 0; rw < 2; rw++){
          float cv = ct[rw][sl][seg];
          cg[rw][0] += cv*q0.x; cg[rw][1] += cv*q0.y; cg[rw][2] += cv*q0.z; cg[rw][3] += cv*q0.w;
          cg[rw][4] += cv*q1.x; cg[rw][5] += cv*q1.y; cg[rw][6] += cv*q1.z; cg[rw][7] += cv*q1.w;
          cg[rw][8] += cv*q2.x;
          cn[rw][0] += cv*q2.y; cn[rw][1] += cv*q2.z; cn[rw][2] += cv*q2.w;
          cn[rw][3] += cv*q3.x; cn[rw][4] += cv*q3.y; cn[rw][5] += cv*q3.z; cn[rw][6] += cv*q3.w;
          cn[rw][7] += cv*q4.x; cn[rw][8] += cv*q4.y;
        }
      }
    }

    // butterfly reduce: 36 independent chains interleave across stages
    #pragma unroll
    for (int rw = 0; rw < 2; rw++){
      #pragma unroll
      for (int e = 0; e < 9; e++){
        float a = cg[rw][e], b = cn[rw][e];
        a = DPP_ADD(a, 0xB1);  b = DPP_ADD(b, 0xB1);   // quad_perm(1,0,3,2)
        a = DPP_ADD(a, 0x4E);  b = DPP_ADD(b, 0x4E);   // quad_perm(2,3,0,1)
        a = DPP_ADD(a, 0x141); b = DPP_ADD(b, 0x141);  // row_half_mirror
        a = DPP_ADD(a, 0x140); b = DPP_ADD(b, 0x140);  // row_mirror
        a += SWZ16(a);         b += SWZ16(b);          // xor 16 (within 32)
        a += __shfl_xor(a, 32, 64);
        b += __shfl_xor(b, 32, 64);
        cg[rw][e] = a; cn[rw][e] = b;
      }
    }

    #pragma unroll
    for (int rw = 0; rw < 2; rw++){
      const int r = 2*p + rw;
      float sd[9], rsd[9], nz[9];
      #pragma unroll
      for (int e = 0; e < 9; e++){
        float x = cn[rw][e];
        float spl = fmaxf(x, 0.f) + __logf(1.0f + __expf(-fabsf(x)));
        sd[e]  = spl + 0.01f;
        rsd[e] = __builtin_amdgcn_rcpf(sd[e]);
        nz[e]  = cg[rw][e] + nzl[rw][e] * sd[e];
      }
      // top-3 (lower index wins ties)
      float v1 = -3.402823e38f, v2 = v1, v3 = v1; int i1 = -1, i2 = -1;
      #pragma unroll
      for (int e = 0; e < 9; e++){
        float v = nz[e];
        if (v > v1){ v3=v2; v2=v1; i2=i1; v1=v; i1=e; }
        else if (v > v2){ v3=v2; v2=v; i2=e; }
        else if (v > v3){ v3=v; }
      }
      float t  = __expf(v2 - v1);
      float g1 = __builtin_amdgcn_rcpf(1.0f + t);
      float g2 = t*g1;
      #pragma unroll
      for (int e = 0; e < 9; e++){
        float thr = (nz[e] > v3) ? v3 : v2;
        float z = (cg[rw][e] - thr)*rsd[e] - 0.1f;       // GATE_MEAN = 0.1
        ldA[e] += phi_fast(z);
        imA[e] += (e==i1) ? g1 : ((e==i2) ? g2 : 0.f);
      }
      // expert mix
      float va0 = pick9(i1, m[rw][0], spv[rw][0][0],spv[rw][1][0],spv[rw][2][0],spv[rw][3][0],
                                      rcv[rw][0][0],rcv[rw][1][0],rcv[rw][2][0],rcv[rw][3][0]);
      float vb0 = pick9(i2, m[rw][0], spv[rw][0][0],spv[rw][1][0],spv[rw][2][0],spv[rw][3][0],
                                      rcv[rw][0][0],rcv[rw][1][0],rcv[rw][2][0],rcv[rw][3][0]);
      outm[(size_t)r*DD + d0] = g1*va0 + g2*vb0;
      if (h1){
        float va1 = pick9(i1, m[rw][1], spv[rw][0][1],spv[rw][1][1],spv[rw][2][1],spv[rw][3][1],
                                        rcv[rw][0][1],rcv[rw][1][1],rcv[rw][2][1],rcv[rw][3][1]);
        float vb1 = pick9(i2, m[rw][1], spv[rw][0][1],spv[rw][1][1],spv[rw][2][1],spv[rw][3][1],
                                        rcv[rw][0][1],rcv[rw][1][1],rcv[rw][2][1],rcv[rw][3][1]);
        outm[(size_t)r*DD + d1] = g1*va1 + g2*vb1;
      }
    }
  }

  if (lane == 0){
    #pragma unroll
    for (int e = 0; e < 9; e++){ sPart[wave][e] = imA[e]; sPart[wave][9+e] = ldA[e]; }
  }
  __syncthreads();
  if (threadIdx.x < 18){
    float s = sPart[0][threadIdx.x] + sPart[1][threadIdx.x]
            + sPart[2][threadIdx.x] + sPart[3][threadIdx.x];
    partials[blockIdx.x*18 + threadIdx.x] = s;
  }
}

// ---------------- Kernel 2: deterministic loss reduction ---------------------
__global__ void k_loss(const float* __restrict__ partials, int nblk,
                       float* __restrict__ dloss)
{
  __shared__ float sS[18][15];
  int t = threadIdx.x;
  if (t < 252){
    int k = t % 18, c = t / 18;   // 14 chunks
    float s = 0.f;
    for (int b = c; b < nblk; b += 14) s += partials[b*18 + k];
    sS[k][c] = s;
  }
  __syncthreads();
  if (t < 18){
    float tot = 0.f;
    #pragma unroll
    for (int c = 0; c < 14; c++) tot += sS[t][c];
    sS[t][14] = tot;
  }
  __syncthreads();
  if (t == 0){
    float mi = 0.f, ml = 0.f;
    #pragma unroll
    for (int e = 0; e < 9; e++){ mi += sS[e][14]; ml += sS[9+e][14]; }
    mi *= (1.f/9.f); ml *= (1.f/9.f);
    float vi = 0.f, vl = 0.f;
    #pragma unroll
    for (int e = 0; e < 9; e++){
      float a = sS[e][14]   - mi; vi += a*a;
      float b = sS[9+e][14] - ml; vl += b*b;
    }
    vi *= (1.f/8.f); vl *= (1.f/8.f);   // ddof=1, n=9
    *dloss = 0.4f * (vi/(mi*mi + 1e-10f) + vl/(ml*ml + 1e-10f));
  }
}

// ---------------- Kernel 3: link-prediction head -----------------------------
__global__ __launch_bounds__(512) void k_edge(
    const float* __restrict__ om,
    const float* __restrict__ sw, const float* __restrict__ sb,
    const float* __restrict__ dw, const float* __restrict__ db,
    const float* __restrict__ ow, const float* __restrict__ ob,
    float* __restrict__ dout, int NE)
{
  __shared__ __align__(4) unsigned short sSW[DD*102];
  __shared__ __align__(4) unsigned short sDW[DD*102];
  __shared__ float sSB[DD], sDB[DD], sOW[DD];

  for (int i = threadIdx.x; i < DD*DD; i += 512){
    int k = i / DD, d = i % DD;
    sSW[d*102 + k] = f2bf(sw[i]);
    sDW[d*102 + k] = f2bf(dw[i]);
  }
  for (int i = threadIdx.x; i < DD; i += 512){ sSB[i]=sb[i]; sDB[i]=db[i]; sOW[i]=ow[i]; }
  __syncthreads();

  const int wave = threadIdx.x >> 6, lane = threadIdx.x & 63;
  const int grp = blockIdx.x*8 + wave;
  const int e0 = grp*4;
  if (e0 >= NE) return;
  const int e0u = __builtin_amdgcn_readfirstlane(e0);
  const float* oS = om + (size_t)e0u*DD;
  const float* oP = om + ((size_t)(NE  + e0u))*DD;
  const float* oN = om + ((size_t)(2*NE + e0u))*DD;
  const int d0 = lane, d1 = lane + 64;
  const bool h1 = (d1 < DD);
  const int dc1 = h1 ? d1 : 0;

  float aS[4][2], aP[4][2], aN[4][2];
  #pragma unroll
  for (int r = 0; r < 4; r++){
    aS[r][0]=0.f; aS[r][1]=0.f; aP[r][0]=0.f; aP[r][1]=0.f; aN[r][0]=0.f; aN[r][1]=0.f;
  }

  for (int k = 0; k < DD; k += 4){
    unsigned uA = *(const unsigned*)&sSW[d0 *102 + k];
    unsigned uB = *(const unsigned*)&sSW[d0 *102 + k + 2];
    unsigned uC = *(const unsigned*)&sSW[dc1*102 + k];
    unsigned uD = *(const unsigned*)&sSW[dc1*102 + k + 2];
    unsigned uE = *(const unsigned*)&sDW[d0 *102 + k];
    unsigned uF = *(const unsigned*)&sDW[d0 *102 + k + 2];
    unsigned uG = *(const unsigned*)&sDW[dc1*102 + k];
    unsigned uH = *(const unsigned*)&sDW[dc1*102 + k + 2];
    float wS00=blo(uA), wS01=bhi(uA), wS02=blo(uB), wS03=bhi(uB);
    float wS10=blo(uC), wS11=bhi(uC), wS12=blo(uD), wS13=bhi(uD);
    float wD00=blo(uE), wD01=bhi(uE), wD02=blo(uF), wD03=bhi(uF);
    float wD10=blo(uG), wD11=bhi(uG), wD12=blo(uH), wD13=bhi(uH);
    #pragma unroll
    for (int r = 0; r < 4; r++){
      float4 ov = *(const float4*)(oS + r*DD + k);
      float4 pv = *(const float4*)(oP + r*DD + k);
      float4 nv = *(const float4*)(oN + r*DD + k);
      aS[r][0] += ov.x*wS00 + ov.y*wS01 + ov.z*wS02 + ov.w*wS03;
      aS[r][1] += ov.x*wS10 + ov.y*wS11 + ov.z*wS12 + ov.w*wS13;
      aP[r][0] += pv.x*wD00 + pv.y*wD01 + pv.z*wD02 + pv.w*wD03;
      aP[r][1] += pv.x*wD10 + pv.y*wD11 + pv.z*wD12 + pv.w*wD13;
      aN[r][0] += nv.x*wD00 + nv.y*wD01 + nv.z*wD02 + nv.w*wD03;
      aN[r][1] += nv.x*wD10 + nv.y*wD11 + nv.z*wD12 + nv.w*wD13;
    }
  }

  float owa = sOW[d0], owb = sOW[dc1];
  float sba = sSB[d0], sbb = sSB[dc1];
  float dba = sDB[d0], dbb = sDB[dc1];
  float ob0 = ob[0];
  #pragma unroll
  for (int r = 0; r < 4; r++){
    float hs0 = aS[r][0] + sba, hp0 = aP[r][0] + dba, hn0 = aN[r][0] + dba;
    float tp = fmaxf(hs0 + hp0, 0.f)*owa;
    float tn = fmaxf(hs0 + hn0, 0.f)*owa;
    if (h1){
      float hs1 = aS[r][1] + sbb, hp1 = aP[r][1] + dbb, hn1 = aN[r][1] + dbb;
      tp += fmaxf(hs1 + hp1, 0.f)*owb;
      tn += fmaxf(hs1 + hn1, 0.f)*owb;
    }
    #pragma unroll
    for (int off = 32; off > 0; off >>= 1){
      tp += __shfl_xor(tp, off, 64);
      tn += __shfl_xor(tn, off, 64);
    }
    if (lane == 0){
      dout[e0 + r]      = tp + ob0;
      dout[NE + e0 + r] = tn + ob0;
    }
  }
}

extern "C" void kernel_launch(void* const* d_in, const int* in_sizes, int n_in,
                              void* d_out, int out_size, void* d_ws, size_t ws_size,
                              hipStream_t stream)
{
  (void)n_in; (void)out_size; (void)ws_size;
  const float* memf  = (const float*)d_in[0];
  const float* recr  = (const float*)d_in[1];
  const float* spar  = (const float*)d_in[2];
  const float* nsrc  = (const float*)d_in[3];
  const float* noise = (const float*)d_in[4];
  const float* degc  = (const float*)d_in[5];
  const float* wg    = (const float*)d_in[6];
  const float* wn    = (const float*)d_in[7];
  const float* sw    = (const float*)d_in[8];
  const float* sb    = (const float*)d_in[9];
  const float* dw    = (const float*)d_in[10];
  const float* db    = (const float*)d_in[11];
  const float* ow    = (const float*)d_in[12];
  const float* ob    = (const float*)d_in[13];
  const int*   deg   = (const int*)d_in[14];

  const int B  = in_sizes[0] / DD;     // 90000
  const int NE = B / 3;                // 30000
  float* outm     = (float*)d_ws;
  float* partials = outm + (size_t)B*DD;
  float* dout     = (float*)d_out;

  k_gating<<<dim3(GB1), dim3(256), 0, stream>>>(memf, recr, spar, nsrc, noise,
                                                degc, wg, wn, deg, outm, partials, B);
  k_loss<<<dim3(1), dim3(256), 0, stream>>>(partials, GB1, dout + 2*NE);
  const int blocks2 = (NE/4 + 7) / 8;  // 938
  k_edge<<<dim3(blocks2), dim3(512), 0, stream>>>(outm, sw, sb, dw, db, ow, ob, dout, NE);
}

// Round 5
// 273.442 us; speedup vs baseline: 5.0347x; 2.4854x over previous
//
#include <hip/hip_runtime.h>
#include <math.h>

#define DD 100

// DPP quad-perm add (ctrl literal)
#define DPP_ADD(v, ctrl) ((v) + __int_as_float(__builtin_amdgcn_update_dpp( \
    0, __float_as_int(v), (ctrl), 0xf, 0xf, true)))

__device__ __forceinline__ float blo(unsigned u){
  union { unsigned i; float f; } c; c.i = u << 16; return c.f;
}
__device__ __forceinline__ float bhi(unsigned u){
  union { unsigned i; float f; } c; c.i = u & 0xFFFF0000u; return c.f;
}
__device__ __forceinline__ unsigned short f2bf(float f){
  unsigned u = __float_as_uint(f);
  unsigned r = (u + 0x7FFFu + ((u >> 16) & 1u)) >> 16;
  return (unsigned short)r;
}
// Phi(z) = 0.5*(1+erf(z/sqrt2)), Abramowitz-Stegun 7.1.26 (|err| ~1e-6)
__device__ __forceinline__ float phi_fast(float z){
  float x  = z * 0.70710678118654752440f;
  float ax = fabsf(x);
  float t  = __builtin_amdgcn_rcpf(1.0f + 0.3275911f*ax);
  float p  = t*(0.254829592f + t*(-0.284496736f + t*(1.421413741f
           + t*(-1.453152027f + t*1.061405429f))));
  float e  = __expf(-ax*ax);
  float erfv = copysignf(1.0f - p*e, x);
  return 0.5f*(1.0f + erfv);
}
__device__ __forceinline__ float4 relu4(float4 v){
  return make_float4(fmaxf(v.x,0.f), fmaxf(v.y,0.f), fmaxf(v.z,0.f), fmaxf(v.w,0.f));
}

// ---------------- Kernel 1: gating only -> gateinfo + loss partials ----------
// 4 lanes per row, 16 rows/wave, 64 rows/wave over 4 passes, 256 rows/block.
// Folded weights in LDS: [d][92] = 5 segs x 18 outputs (+2 pad), 36.8 KB.
// cat@W = mem@(W0+W3) + rs@(W1+W3) + rr@(W2+W3) + x2@W4 + ns@W5.
__global__ __launch_bounds__(256) void k_gate(
    const float* __restrict__ memf, const float* __restrict__ recr,
    const float* __restrict__ spar, const float* __restrict__ nsrc,
    const float* __restrict__ noise, const float* __restrict__ degc,
    const float* __restrict__ wg,   const float* __restrict__ wn,
    const int*   __restrict__ degree,
    float4* __restrict__ gateinfo, float* __restrict__ partials, int B)
{
  __shared__ __align__(16) float sWF[100*92];   // 36.8 KB
  __shared__ __align__(16) float sC0[DD], sC1[DD];
  __shared__ float sPart[4][18];

  for (int i = threadIdx.x; i < 9000; i += 256){
    int d = i / 90, j2 = i % 90;
    int seg = j2 / 18, e = j2 % 18;
    int rowA = (seg==0) ? d : (seg==1) ? 100+d : (seg==2) ? 200+d
             : (seg==3) ? 400+d : 500+d;
    const float* W = (e < 9) ? wg : wn;
    int ee = (e < 9) ? e : e - 9;
    float v = W[rowA*9 + ee] + ((seg < 3) ? W[(300+d)*9 + ee] : 0.f);
    sWF[d*92 + j2] = v;
  }
  for (int i = threadIdx.x; i < DD; i += 256){ sC0[i]=degc[2*i]; sC1[i]=degc[2*i+1]; }
  __syncthreads();

  const int wave = threadIdx.x >> 6, lane = threadIdx.x & 63;
  const int fq = lane & 3, rl = lane >> 2;
  const float4* sC04 = (const float4*)sC0;
  const float4* sC14 = (const float4*)sC1;

  float ldA[9], imA[9];
  #pragma unroll
  for (int e = 0; e < 9; e++){ ldA[e]=0.f; imA[e]=0.f; }

  for (int pass = 0; pass < 4; pass++){
    const int row = ((blockIdx.x*4 + wave)*4 + pass)*16 + rl;
    const bool valid = row < B;
    const int rc = valid ? row : B-1;
    const float* pm = memf + (size_t)rc*DD;
    const float* ps = spar + (size_t)rc*4*DD;
    const float* pr = recr + (size_t)rc*4*DD;
    const float* pn = nsrc + (size_t)rc*DD;
    float ldg = __logf((float)degree[rc] + 1.0f);

    float cg[9], cn[9];
    #pragma unroll
    for (int e = 0; e < 9; e++){ cg[e]=0.f; cn[e]=0.f; }

    for (int k = 0; k < 7; k++){
      int c = fq + 4*k;
      float fz = (c < 25) ? 1.f : 0.f;
      int ce = (c < 25) ? c : 0;
      float4 me = *(const float4*)(pm + 4*ce);
      float4 s0 = *(const float4*)(ps + 0*DD + 4*ce);
      float4 s1 = *(const float4*)(ps + 1*DD + 4*ce);
      float4 s2 = *(const float4*)(ps + 2*DD + 4*ce);
      float4 s3 = *(const float4*)(ps + 3*DD + 4*ce);
      float4 r0 = *(const float4*)(pr + 0*DD + 4*ce);
      float4 r1 = *(const float4*)(pr + 1*DD + 4*ce);
      float4 r2 = *(const float4*)(pr + 2*DD + 4*ce);
      float4 r3 = *(const float4*)(pr + 3*DD + 4*ce);
      float4 nv = *(const float4*)(pn + 4*ce);
      float4 c04 = sC04[ce], c14 = sC14[ce];

      float4 m4 = relu4(me);
      float4 sc = make_float4(c04.x + ldg*c14.x, c04.y + ldg*c14.y,
                              c04.z + ldg*c14.z, c04.w + ldg*c14.w);
      float4 rs4 = make_float4((s0.x+s1.x+s2.x+s3.x)*0.25f*sc.x,
                               (s0.y+s1.y+s2.y+s3.y)*0.25f*sc.y,
                               (s0.z+s1.z+s2.z+s3.z)*0.25f*sc.z,
                               (s0.w+s1.w+s2.w+s3.w)*0.25f*sc.w);
      float4 a0 = relu4(r0), a1 = relu4(r1), a2 = relu4(r2), a3 = relu4(r3);
      float4 rr4 = make_float4((a0.x+a1.x+a2.x+a3.x)*0.25f,
                               (a0.y+a1.y+a2.y+a3.y)*0.25f,
                               (a0.z+a1.z+a2.z+a3.z)*0.25f,
                               (a0.w+a1.w+a2.w+a3.w)*0.25f);
      m4.x*=fz; m4.y*=fz; m4.z*=fz; m4.w*=fz;
      rs4.x*=fz; rs4.y*=fz; rs4.z*=fz; rs4.w*=fz;
      rr4.x*=fz; rr4.y*=fz; rr4.z*=fz; rr4.w*=fz;
      float4 ns4 = make_float4(nv.x*fz, nv.y*fz, nv.z*fz, nv.w*fz);
      float4 x24 = make_float4(m4.x*rs4.x*rr4.x, m4.y*rs4.y*rr4.y,
                               m4.z*rs4.z*rr4.z, m4.w*rs4.w*rr4.w);

      #pragma unroll
      for (int j = 0; j < 4; j++){
        const float der0 = (j==0)?m4.x :(j==1)?m4.y :(j==2)?m4.z :m4.w;
        const float der1 = (j==0)?rs4.x:(j==1)?rs4.y:(j==2)?rs4.z:rs4.w;
        const float der2 = (j==0)?rr4.x:(j==1)?rr4.y:(j==2)?rr4.z:rr4.w;
        const float der3 = (j==0)?x24.x:(j==1)?x24.y:(j==2)?x24.z:x24.w;
        const float der4 = (j==0)?ns4.x:(j==1)?ns4.y:(j==2)?ns4.z:ns4.w;
        const float4* wpj = (const float4*)(sWF + (4*ce + j)*92);
        #pragma unroll
        for (int t = 0; t < 23; t++){
          float4 w = wpj[t];
          #pragma unroll
          for (int u = 0; u < 4; u++){
            const int ww = 4*t + u;
            if (ww < 90){
              const int seg = ww/18, e = ww%18;
              float wv = (u==0)?w.x:(u==1)?w.y:(u==2)?w.z:w.w;
              float dv = (seg==0)?der0:(seg==1)?der1:(seg==2)?der2:(seg==3)?der3:der4;
              if (e < 9) cg[e] += dv*wv; else cn[e-9] += dv*wv;
            }
          }
        }
      }
    }

    // quad reduce: after 2 stages, all 4 lanes of a group hold the row sums
    #pragma unroll
    for (int e = 0; e < 9; e++){
      cg[e] = DPP_ADD(cg[e], 0xB1); cg[e] = DPP_ADD(cg[e], 0x4E);
      cn[e] = DPP_ADD(cn[e], 0xB1); cn[e] = DPP_ADD(cn[e], 0x4E);
    }

    float sd[9], rsd[9], nz[9];
    #pragma unroll
    for (int e = 0; e < 9; e++){
      float x = cn[e];
      float spl = fmaxf(x, 0.f) + __logf(1.0f + __expf(-fabsf(x)));
      sd[e]  = spl + 0.01f;
      rsd[e] = __builtin_amdgcn_rcpf(sd[e]);
      nz[e]  = cg[e] + noise[(size_t)rc*9 + e] * sd[e];
    }
    float v1 = -3.402823e38f, v2 = v1, v3 = v1; int i1 = -1, i2 = -1;
    #pragma unroll
    for (int e = 0; e < 9; e++){
      float v = nz[e];
      if (v > v1){ v3=v2; v2=v1; i2=i1; v1=v; i1=e; }
      else if (v > v2){ v3=v2; v2=v; i2=e; }
      else if (v > v3){ v3=v; }
    }
    float t  = __expf(v2 - v1);
    float g1 = __builtin_amdgcn_rcpf(1.0f + t);
    float g2 = t*g1;
    if (valid){
      #pragma unroll
      for (int e = 0; e < 9; e++){
        float thr = (nz[e] > v3) ? v3 : v2;
        float z = (cg[e] - thr)*rsd[e] - 0.1f;           // GATE_MEAN = 0.1
        ldA[e] += phi_fast(z);
        imA[e] += (e==i1) ? g1 : ((e==i2) ? g2 : 0.f);
      }
      if (fq == 0)
        gateinfo[row] = make_float4(g1, g2, __int_as_float(i1), __int_as_float(i2));
    }
  }

  // reduce across the 16 groups (quad bits untouched -> no duplication factor)
  #pragma unroll
  for (int e = 0; e < 9; e++){
    #pragma unroll
    for (int off = 4; off < 64; off <<= 1){
      ldA[e] += __shfl_xor(ldA[e], off, 64);
      imA[e] += __shfl_xor(imA[e], off, 64);
    }
  }
  if (lane == 0){
    #pragma unroll
    for (int e = 0; e < 9; e++){ sPart[wave][e] = imA[e]; sPart[wave][9+e] = ldA[e]; }
  }
  __syncthreads();
  if (threadIdx.x < 18){
    float s = sPart[0][threadIdx.x] + sPart[1][threadIdx.x]
            + sPart[2][threadIdx.x] + sPart[3][threadIdx.x];
    partials[blockIdx.x*18 + threadIdx.x] = s;
  }
}

// ---------------- Kernel 2: expert mix -> outm (reads only chosen experts) ---
__global__ __launch_bounds__(256) void k_mix(
    const float* __restrict__ memf, const float* __restrict__ recr,
    const float* __restrict__ spar, const float* __restrict__ degc,
    const int* __restrict__ degree, const float4* __restrict__ gateinfo,
    float* __restrict__ outm, int B)
{
  const int total = B*25;
  for (int idx = blockIdx.x*256 + threadIdx.x; idx < total; idx += gridDim.x*256){
    int row = idx / 25, q = idx - row*25;
    float4 gi = gateinfo[row];
    float gv[2] = {gi.x, gi.y};
    int   ei[2] = {__float_as_int(gi.z), __float_as_int(gi.w)};
    float4 acc = make_float4(0.f,0.f,0.f,0.f);
    #pragma unroll
    for (int s = 0; s < 2; s++){
      int e = ei[s]; float g = gv[s];
      float4 v;
      if (e == 0){
        v = relu4(*(const float4*)(memf + (size_t)row*DD + 4*q));
      } else if (e < 5){
        float ldg = __logf((float)degree[row] + 1.0f);
        float4 ca = *(const float4*)(degc + 8*q);       // c0,c1,c0,c1
        float4 cb = *(const float4*)(degc + 8*q + 4);
        float4 sv = *(const float4*)(spar + ((size_t)row*4 + (e-1))*DD + 4*q);
        v = make_float4(sv.x*(ca.x + ldg*ca.y), sv.y*(ca.z + ldg*ca.w),
                        sv.z*(cb.x + ldg*cb.y), sv.w*(cb.z + ldg*cb.w));
      } else {
        v = relu4(*(const float4*)(recr + ((size_t)row*4 + (e-5))*DD + 4*q));
      }
      acc.x += g*v.x; acc.y += g*v.y; acc.z += g*v.z; acc.w += g*v.w;
    }
    ((float4*)outm)[(size_t)row*25 + q] = acc;
  }
}

// ---------------- Kernel 3: deterministic loss reduction ---------------------
__global__ void k_loss(const float* __restrict__ partials, int nblk,
                       float* __restrict__ dloss)
{
  __shared__ float sS[18][15];
  int t = threadIdx.x;
  if (t < 252){
    int k = t % 18, c = t / 18;   // 14 chunks
    float s = 0.f;
    for (int b = c; b < nblk; b += 14) s += partials[b*18 + k];
    sS[k][c] = s;
  }
  __syncthreads();
  if (t < 18){
    float tot = 0.f;
    #pragma unroll
    for (int c = 0; c < 14; c++) tot += sS[t][c];
    sS[t][14] = tot;
  }
  __syncthreads();
  if (t == 0){
    float mi = 0.f, ml = 0.f;
    #pragma unroll
    for (int e = 0; e < 9; e++){ mi += sS[e][14]; ml += sS[9+e][14]; }
    mi *= (1.f/9.f); ml *= (1.f/9.f);
    float vi = 0.f, vl = 0.f;
    #pragma unroll
    for (int e = 0; e < 9; e++){
      float a = sS[e][14]   - mi; vi += a*a;
      float b = sS[9+e][14] - ml; vl += b*b;
    }
    vi *= (1.f/8.f); vl *= (1.f/8.f);   // ddof=1, n=9
    *dloss = 0.4f * (vi/(mi*mi + 1e-10f) + vl/(ml*ml + 1e-10f));
  }
}

// ---------------- Kernel 4: link-prediction head -----------------------------
__global__ __launch_bounds__(512) void k_edge(
    const float* __restrict__ om,
    const float* __restrict__ sw, const float* __restrict__ sb,
    const float* __restrict__ dw, const float* __restrict__ db,
    const float* __restrict__ ow, const float* __restrict__ ob,
    float* __restrict__ dout, int NE)
{
  __shared__ __align__(4) unsigned short sSW[DD*102];
  __shared__ __align__(4) unsigned short sDW[DD*102];
  __shared__ float sSB[DD], sDB[DD], sOW[DD];

  for (int i = threadIdx.x; i < DD*DD; i += 512){
    int k = i / DD, d = i % DD;
    sSW[d*102 + k] = f2bf(sw[i]);
    sDW[d*102 + k] = f2bf(dw[i]);
  }
  for (int i = threadIdx.x; i < DD; i += 512){ sSB[i]=sb[i]; sDB[i]=db[i]; sOW[i]=ow[i]; }
  __syncthreads();

  const int wave = threadIdx.x >> 6, lane = threadIdx.x & 63;
  const int grp = blockIdx.x*8 + wave;
  const int e0 = grp*4;
  if (e0 >= NE) return;
  const int e0u = __builtin_amdgcn_readfirstlane(e0);
  const float* oS = om + (size_t)e0u*DD;
  const float* oP = om + ((size_t)(NE  + e0u))*DD;
  const float* oN = om + ((size_t)(2*NE + e0u))*DD;
  const int d0 = lane, d1 = lane + 64;
  const bool h1 = (d1 < DD);
  const int dc1 = h1 ? d1 : 0;

  float aS[4][2], aP[4][2], aN[4][2];
  #pragma unroll
  for (int r = 0; r < 4; r++){
    aS[r][0]=0.f; aS[r][1]=0.f; aP[r][0]=0.f; aP[r][1]=0.f; aN[r][0]=0.f; aN[r][1]=0.f;
  }

  for (int k = 0; k < DD; k += 4){
    unsigned uA = *(const unsigned*)&sSW[d0 *102 + k];
    unsigned uB = *(const unsigned*)&sSW[d0 *102 + k + 2];
    unsigned uC = *(const unsigned*)&sSW[dc1*102 + k];
    unsigned uD = *(const unsigned*)&sSW[dc1*102 + k + 2];
    unsigned uE = *(const unsigned*)&sDW[d0 *102 + k];
    unsigned uF = *(const unsigned*)&sDW[d0 *102 + k + 2];
    unsigned uG = *(const unsigned*)&sDW[dc1*102 + k];
    unsigned uH = *(const unsigned*)&sDW[dc1*102 + k + 2];
    float wS00=blo(uA), wS01=bhi(uA), wS02=blo(uB), wS03=bhi(uB);
    float wS10=blo(uC), wS11=bhi(uC), wS12=blo(uD), wS13=bhi(uD);
    float wD00=blo(uE), wD01=bhi(uE), wD02=blo(uF), wD03=bhi(uF);
    float wD10=blo(uG), wD11=bhi(uG), wD12=blo(uH), wD13=bhi(uH);
    #pragma unroll
    for (int r = 0; r < 4; r++){
      float4 ov = *(const float4*)(oS + r*DD + k);
      float4 pv = *(const float4*)(oP + r*DD + k);
      float4 nv = *(const float4*)(oN + r*DD + k);
      aS[r][0] += ov.x*wS00 + ov.y*wS01 + ov.z*wS02 + ov.w*wS03;
      aS[r][1] += ov.x*wS10 + ov.y*wS11 + ov.z*wS12 + ov.w*wS13;
      aP[r][0] += pv.x*wD00 + pv.y*wD01 + pv.z*wD02 + pv.w*wD03;
      aP[r][1] += pv.x*wD10 + pv.y*wD11 + pv.z*wD12 + pv.w*wD13;
      aN[r][0] += nv.x*wD00 + nv.y*wD01 + nv.z*wD02 + nv.w*wD03;
      aN[r][1] += nv.x*wD10 + nv.y*wD11 + nv.z*wD12 + nv.w*wD13;
    }
  }

  float owa = sOW[d0], owb = sOW[dc1];
  float sba = sSB[d0], sbb = sSB[dc1];
  float dba = sDB[d0], dbb = sDB[dc1];
  float ob0 = ob[0];
  #pragma unroll
  for (int r = 0; r < 4; r++){
    float hs0 = aS[r][0] + sba, hp0 = aP[r][0] + dba, hn0 = aN[r][0] + dba;
    float tp = fmaxf(hs0 + hp0, 0.f)*owa;
    float tn = fmaxf(hs0 + hn0, 0.f)*owa;
    if (h1){
      float hs1 = aS[r][1] + sbb, hp1 = aP[r][1] + dbb, hn1 = aN[r][1] + dbb;
      tp += fmaxf(hs1 + hp1, 0.f)*owb;
      tn += fmaxf(hs1 + hn1, 0.f)*owb;
    }
    #pragma unroll
    for (int off = 32; off > 0; off >>= 1){
      tp += __shfl_xor(tp, off, 64);
      tn += __shfl_xor(tn, off, 64);
    }
    if (lane == 0){
      dout[e0 + r]      = tp + ob0;
      dout[NE + e0 + r] = tn + ob0;
    }
  }
}

extern "C" void kernel_launch(void* const* d_in, const int* in_sizes, int n_in,
                              void* d_out, int out_size, void* d_ws, size_t ws_size,
                              hipStream_t stream)
{
  (void)n_in; (void)out_size; (void)ws_size;
  const float* memf  = (const float*)d_in[0];
  const float* recr  = (const float*)d_in[1];
  const float* spar  = (const float*)d_in[2];
  const float* nsrc  = (const float*)d_in[3];
  const float* noise = (const float*)d_in[4];
  const float* degc  = (const float*)d_in[5];
  const float* wg    = (const float*)d_in[6];
  const float* wn    = (const float*)d_in[7];
  const float* sw    = (const float*)d_in[8];
  const float* sb    = (const float*)d_in[9];
  const float* dw    = (const float*)d_in[10];
  const float* db    = (const float*)d_in[11];
  const float* ow    = (const float*)d_in[12];
  const float* ob    = (const float*)d_in[13];
  const int*   deg   = (const int*)d_in[14];

  const int B  = in_sizes[0] / DD;     // 90000
  const int NE = B / 3;                // 30000
  const int blocksA = (B + 255) / 256; // 352

  float*  outm     = (float*)d_ws;                              // 9M floats
  float*  partials = outm + (size_t)B*DD;                       // blocksA*18
  float4* gateinfo = (float4*)(partials + (size_t)blocksA*18);  // B float4 (16B-aligned)
  float*  dout     = (float*)d_out;

  k_gate<<<dim3(blocksA), dim3(256), 0, stream>>>(memf, recr, spar, nsrc, noise,
                                                  degc, wg, wn, deg, gateinfo,
                                                  partials, B);
  k_mix<<<dim3(2048), dim3(256), 0, stream>>>(memf, recr, spar, degc, deg,
                                              gateinfo, outm, B);
  k_loss<<<dim3(1), dim3(256), 0, stream>>>(partials, blocksA, dout + 2*NE);
  const int blocks2 = (NE/4 + 7) / 8;  // 938
  k_edge<<<dim3(blocks2), dim3(512), 0, stream>>>(outm, sw, sb, dw, db, ow, ob, dout, NE);
}